// Round 2
// baseline (104.566 us; speedup 1.0000x reference)
//
#include <hip/hip_runtime.h>
#include <math.h>

// Problem constants (fixed by reference setup_inputs)
#define NN 32768
#define LL 256      // K dimension (leaves)
#define CC 64       // output cols (classes)
#define EPSV 1e-12f

typedef __attribute__((ext_vector_type(8))) short short8;   // 8 bf16 = 4 VGPRs (MFMA A/B frag)
typedef __attribute__((ext_vector_type(4))) float f32x4;    // MFMA C/D frag

// Split fp32 x (>0) into bf16 hi + bf16 lo such that hi+lo ~= x to ~2^-17 rel.
// hi = truncate(x), lo = truncate(x - hi)  (x - hi is exact in fp32).
__device__ inline void bf16_split(float x, short& h, short& l) {
    union { float f; unsigned u; } cv;
    cv.f = x;
    unsigned hu = cv.u & 0xffff0000u;
    h = (short)(cv.u >> 16);
    union { unsigned u; float f; } ch;
    ch.u = hu;
    float xl = x - ch.f;          // exact (low 16 mantissa bits of x)
    union { float f; unsigned u; } cl;
    cl.f = xl;
    l = (short)(cl.u >> 16);
}

// ---------------------------------------------------------------------------
// Prep kernel: softmax(leaf_scores) rows -> bf16 hi/lo, stored in EXACT MFMA
// B-fragment order for mfma_f32_16x16x32_bf16.
//   B-frag layout: lane holds B[k = quad*8+j][n = lane&15], j = 0..7.
//   ws layout: region r = (s*4 + t)*2 + h  (s = k-step 0..7, t = n-tile 0..3,
//   h = 0 hi / 1 lo), each region = 64 lanes * 16 B = 1 KB. Total 64 KB.
// Grid: 8 blocks (one per k-step s), 64 threads.
// ---------------------------------------------------------------------------
__global__ __launch_bounds__(64) void prep_kernel(
    const float* __restrict__ scores, float* __restrict__ wsB) {
    __shared__ float Qs[32][64];
    const int s = blockIdx.x;
    const int lane = threadIdx.x;

    // softmax of rows s*32 .. s*32+31 (lane = column)
    for (int r = 0; r < 32; ++r) {
        float v = scores[(size_t)(s * 32 + r) * CC + lane];
        float mx = v;
        #pragma unroll
        for (int off = 32; off > 0; off >>= 1) mx = fmaxf(mx, __shfl_xor(mx, off));
        float e = expf(v - mx);
        float sum = e;
        #pragma unroll
        for (int off = 32; off > 0; off >>= 1) sum += __shfl_xor(sum, off);
        Qs[r][lane] = e / sum;
    }
    __syncthreads();

    const int quad = lane >> 4;
    const int n = lane & 15;
    short8* wsB8 = (short8*)wsB;
    #pragma unroll
    for (int t = 0; t < 4; ++t) {
        short8 hi, lo;
        #pragma unroll
        for (int j = 0; j < 8; ++j) {
            short h, l;
            bf16_split(Qs[quad * 8 + j][t * 16 + n], h, l);
            hi[j] = h; lo[j] = l;
        }
        const int rgn = (s * 4 + t) * 2;              // hi region index
        wsB8[(rgn + 0) * 64 + lane] = hi;             // 64 short8 per 1 KB region
        wsB8[(rgn + 1) * 64 + lane] = lo;
    }
}

// ---------------------------------------------------------------------------
// Main kernel: out = log( clamp(mu,eps) @ Q )  via 3-term bf16-split MFMA.
// 512 blocks x 256 threads (4 waves). Wave: 16 rows x 64 cols, full K=256.
// B-frags resident in LDS (64 KB, copied once); A-frags global->reg->split.
// ---------------------------------------------------------------------------
__global__ __launch_bounds__(256) void leaf_mix_mfma_kernel(
    const float* __restrict__ mu, const float* __restrict__ wsB,
    float* __restrict__ out) {
    __shared__ float Bs[16384];   // 64 KB of pre-swizzled B fragments

    const int tid = threadIdx.x;
    // one-time B stage: 256 threads x 16 iters x 16 B = 64 KB (L2-hot)
    {
        const float4* src = (const float4*)wsB;
        float4* dst = (float4*)Bs;
        #pragma unroll
        for (int i = 0; i < 16; ++i) dst[tid + 256 * i] = src[tid + 256 * i];
    }
    __syncthreads();

    const int wid = tid >> 6;
    const int lane = tid & 63;
    const int quad = lane >> 4;
    const int m = lane & 15;

    // A-frag row for this lane; k offset = s*32 + quad*8 + j
    const size_t row = (size_t)blockIdx.x * 64 + wid * 16 + m;
    const float* arow = mu + row * LL + quad * 8;

    // issue all A loads up front (16 rows x 256 k per wave; 8 f32/lane/step)
    float4 a[16];
    #pragma unroll
    for (int s = 0; s < 8; ++s) {
        a[2 * s]     = *(const float4*)(arow + s * 32);
        a[2 * s + 1] = *(const float4*)(arow + s * 32 + 4);
    }

    f32x4 acc[4] = {{0.f, 0.f, 0.f, 0.f}, {0.f, 0.f, 0.f, 0.f},
                    {0.f, 0.f, 0.f, 0.f}, {0.f, 0.f, 0.f, 0.f}};

    #pragma unroll
    for (int s = 0; s < 8; ++s) {
        float f[8] = {a[2 * s].x, a[2 * s].y, a[2 * s].z, a[2 * s].w,
                      a[2 * s + 1].x, a[2 * s + 1].y, a[2 * s + 1].z, a[2 * s + 1].w};
        short8 ahi, alo;
        #pragma unroll
        for (int e = 0; e < 8; ++e) {
            short h, l;
            bf16_split(fmaxf(f[e], EPSV), h, l);
            ahi[e] = h; alo[e] = l;
        }
        #pragma unroll
        for (int t = 0; t < 4; ++t) {
            const short8 bhi = ((const short8*)(Bs + (s * 4 + t) * 512))[lane];
            const short8 blo = ((const short8*)(Bs + (s * 4 + t) * 512 + 256))[lane];
            acc[t] = __builtin_amdgcn_mfma_f32_16x16x32_bf16(ahi, bhi, acc[t], 0, 0, 0);
            acc[t] = __builtin_amdgcn_mfma_f32_16x16x32_bf16(alo, bhi, acc[t], 0, 0, 0);
            acc[t] = __builtin_amdgcn_mfma_f32_16x16x32_bf16(ahi, blo, acc[t], 0, 0, 0);
        }
    }

    // epilogue: C/D layout col = lane&15, row = quad*4 + reg
    const size_t outRow0 = (size_t)blockIdx.x * 64 + wid * 16 + quad * 4;
    #pragma unroll
    for (int t = 0; t < 4; ++t)
        #pragma unroll
        for (int r = 0; r < 4; ++r)
            out[(outRow0 + r) * CC + t * 16 + m] = logf(acc[t][r]);
}

extern "C" void kernel_launch(void* const* d_in, const int* in_sizes, int n_in,
                              void* d_out, int out_size, void* d_ws, size_t ws_size,
                              hipStream_t stream) {
    const float* mu     = (const float*)d_in[0];   // (32768, 256) f32
    const float* scores = (const float*)d_in[1];   // (256, 64)    f32
    float* out = (float*)d_out;                    // (32768, 64)  f32
    float* wsB = (float*)d_ws;                     // 64 KB: swizzled B frags

    prep_kernel<<<8, 64, 0, stream>>>(scores, wsB);
    leaf_mix_mfma_kernel<<<NN / 64, 256, 0, stream>>>(mu, wsB, out);
}

// Round 3
// 79.523 us; speedup vs baseline: 1.3149x; 1.3149x over previous
//
#include <hip/hip_runtime.h>
#include <math.h>

// Problem constants (fixed by reference setup_inputs)
#define NN 32768
#define LL 256      // K dimension (leaves)
#define CC 64       // output cols (classes)
#define EPSV 1e-12f

typedef __attribute__((ext_vector_type(8))) _Float16 half8;  // MFMA A/B frag (4 VGPRs)
typedef __attribute__((ext_vector_type(4))) float f32x4;     // MFMA C/D frag

// ---------------------------------------------------------------------------
// Prep kernel: softmax(leaf_scores) rows -> fp16, scattered directly into
// MFMA B-fragment order for mfma_f32_16x16x32_f16.
//   B-frag: lane (q,m) holds B[k = s*32 + q*8 + j][n = t*16 + m], j = 0..7.
//   ws region (s,t): 64 lanes x 8 fp16 = 1 KB; 32 regions = 32 KB total.
// Grid: 256 blocks (one leaf-row each) x 64 threads (one class each).
// ---------------------------------------------------------------------------
__global__ __launch_bounds__(64) void prep_kernel(
    const float* __restrict__ scores, _Float16* __restrict__ wsB) {
    const int l = blockIdx.x;    // leaf row
    const int k = threadIdx.x;   // class col
    float v = scores[(size_t)l * CC + k];
    float mx = v;
    #pragma unroll
    for (int off = 32; off > 0; off >>= 1) mx = fmaxf(mx, __shfl_xor(mx, off));
    float e = expf(v - mx);
    float sum = e;
    #pragma unroll
    for (int off = 32; off > 0; off >>= 1) sum += __shfl_xor(sum, off);
    _Float16 h = (_Float16)(e / sum);

    const int s = l >> 5;          // k-step
    const int w = l & 31;
    const int q = w >> 3;          // quad within frag
    const int j = w & 7;           // element within frag
    const int t = k >> 4;          // n-tile
    const int m = k & 15;          // n within tile
    // fp16 index: region*(64 lanes * 8) + lane*8 + j
    wsB[((s * 4 + t) * 64 + q * 16 + m) * 8 + j] = h;
}

// ---------------------------------------------------------------------------
// Main kernel: out = log( clamp(mu,eps) @ Q )  via 2-term fp16-split MFMA:
//   a = ahi + alo (fp16 split), b = fp16(q):  a*b ~= ahi*b + alo*b  (rel ~2^-12)
// 512 blocks x 256 threads (4 waves). Wave: 16 rows x 64 cols, full K=256.
// Bs = 32 KB (one copy from ws per block); A-frags loaded global->reg first
// so HBM latency overlaps Bs staging + barrier.
// ---------------------------------------------------------------------------
__global__ __launch_bounds__(256) void leaf_mix_mfma_kernel(
    const float* __restrict__ mu, const float4* __restrict__ wsB,
    float* __restrict__ out) {
    __shared__ float Bs[8192];   // 32 KB of pre-swizzled fp16 B fragments

    const int tid = threadIdx.x;
    const int wid = tid >> 6;
    const int lane = tid & 63;
    const int quad = lane >> 4;
    const int m = lane & 15;

    // ---- A loads first (HBM): lane m holds row, k-window = s*32 + quad*8 ----
    const size_t row = (size_t)blockIdx.x * 64 + wid * 16 + m;
    const float* arow = mu + row * LL + quad * 8;
    float4 a[16];
    #pragma unroll
    for (int s = 0; s < 8; ++s) {
        a[2 * s]     = *(const float4*)(arow + s * 32);
        a[2 * s + 1] = *(const float4*)(arow + s * 32 + 4);
    }

    // ---- stage Bs (32 KB from ws, L2-hot): 256 thr x 8 x 16 B ----
    {
        float4* dst = (float4*)Bs;
        #pragma unroll
        for (int i = 0; i < 8; ++i) dst[tid + 256 * i] = wsB[tid + 256 * i];
    }
    __syncthreads();

    f32x4 acc[4] = {{0.f, 0.f, 0.f, 0.f}, {0.f, 0.f, 0.f, 0.f},
                    {0.f, 0.f, 0.f, 0.f}, {0.f, 0.f, 0.f, 0.f}};

    #pragma unroll
    for (int s = 0; s < 8; ++s) {
        const float f[8] = {a[2 * s].x, a[2 * s].y, a[2 * s].z, a[2 * s].w,
                            a[2 * s + 1].x, a[2 * s + 1].y, a[2 * s + 1].z, a[2 * s + 1].w};
        half8 ahi, alo;
        #pragma unroll
        for (int e = 0; e < 8; ++e) {
            const float x = fmaxf(f[e], EPSV);
            const _Float16 h = (_Float16)x;
            ahi[e] = h;
            alo[e] = (_Float16)(x - (float)h);
        }
        #pragma unroll
        for (int t = 0; t < 4; ++t) {
            const half8 b = ((const half8*)(Bs + (s * 4 + t) * 256))[lane];
            acc[t] = __builtin_amdgcn_mfma_f32_16x16x32_f16(ahi, b, acc[t], 0, 0, 0);
            acc[t] = __builtin_amdgcn_mfma_f32_16x16x32_f16(alo, b, acc[t], 0, 0, 0);
        }
    }

    // ---- epilogue: C/D layout col = lane&15, row = quad*4 + reg (verified R2) ----
    const size_t outRow0 = (size_t)blockIdx.x * 64 + wid * 16 + quad * 4;
    #pragma unroll
    for (int t = 0; t < 4; ++t)
        #pragma unroll
        for (int r = 0; r < 4; ++r)
            out[(outRow0 + r) * CC + t * 16 + m] = logf(acc[t][r]);
}

extern "C" void kernel_launch(void* const* d_in, const int* in_sizes, int n_in,
                              void* d_out, int out_size, void* d_ws, size_t ws_size,
                              hipStream_t stream) {
    const float* mu     = (const float*)d_in[0];   // (32768, 256) f32
    const float* scores = (const float*)d_in[1];   // (256, 64)    f32
    float* out = (float*)d_out;                    // (32768, 64)  f32

    prep_kernel<<<LL, CC, 0, stream>>>(scores, (_Float16*)d_ws);
    leaf_mix_mfma_kernel<<<NN / 64, 256, 0, stream>>>(mu, (const float4*)d_ws, out);
}